// Round 16
// baseline (1166.724 us; speedup 1.0000x reference)
//
#include <hip/hip_runtime.h>
#include <hip/hip_fp16.h>
#include <math.h>
#include <string.h>

// ---------------- problem constants ----------------
#define E_EDGES 40000
#define N_NODES 80000
#define NEF 10        // edges per block (fused kernel, VT=2 @ 256 threads)

// ---- sign knobs (verified correct in round 1) ----
#define S111 1.0
#define S122 1.0
#define S212 1.0
#define S221 1.0
#define S222 1.0

struct W3J { float v[615]; };

typedef __attribute__((ext_vector_type(8))) short bf16x8;
typedef __attribute__((ext_vector_type(4))) float f32x4;
typedef __attribute__((ext_vector_type(2))) float f32x2;

// ---------------- host: build W3J tensors (verified round 1) ----------------
static void build_w3j(W3J& w) {
    const double s3 = sqrt(3.0), s5 = sqrt(5.0), s15 = sqrt(15.0);
    struct Mono { int a, b, c; double co; };
    Mono Y[3][5][3]; int nm[3][5];
    for (int l = 0; l < 3; l++) for (int c = 0; c < 5; c++) nm[l][c] = 0;
    nm[0][0] = 1; Y[0][0][0] = Mono{0,0,0,1.0};
    nm[1][0] = 1; Y[1][0][0] = Mono{1,0,0,s3};
    nm[1][1] = 1; Y[1][1][0] = Mono{0,1,0,s3};
    nm[1][2] = 1; Y[1][2][0] = Mono{0,0,1,s3};
    nm[2][0] = 1; Y[2][0][0] = Mono{1,0,1,s15};
    nm[2][1] = 1; Y[2][1][0] = Mono{1,1,0,s15};
    nm[2][2] = 3; Y[2][2][0] = Mono{0,2,0,s5};  Y[2][2][1] = Mono{2,0,0,-0.5*s5}; Y[2][2][2] = Mono{0,0,2,-0.5*s5};
    nm[2][3] = 1; Y[2][3][0] = Mono{0,1,1,s15};
    nm[2][4] = 2; Y[2][4][0] = Mono{0,0,2,0.5*s15}; Y[2][4][1] = Mono{2,0,0,-0.5*s15};

    static const int PL[15][3] = {{0,0,0},{0,1,1},{0,2,2},{1,0,1},{1,1,0},{1,1,1},{1,1,2},{1,2,1},
                                  {1,2,2},{2,0,2},{2,1,1},{2,1,2},{2,2,0},{2,2,1},{2,2,2}};
    static const int OFF[15]  = {0,1,10,35,44,53,80,125,170,245,270,315,390,415,490};
    static const int ANCH[15] = {0,0,0,0,0,5,22,22,29,0,22,9,0,13,2};
    const double ASGN[15] = {1,1,1,1,1, S111, 1,1, S122, 1,1, S212, 1, S221, S222};

    auto dfact = [](int n) { double r = 1.0; for (int k = n; k > 1; k -= 2) r *= k; return r; };

    double Mm[5][3][3]; memset(Mm, 0, sizeof(Mm));
    const double mh = s15 * 0.5;
    Mm[0][0][2] = Mm[0][2][0] = mh;
    Mm[1][0][1] = Mm[1][1][0] = mh;
    Mm[2][0][0] = -0.5*s5; Mm[2][1][1] = s5; Mm[2][2][2] = -0.5*s5;
    Mm[3][1][2] = Mm[3][2][1] = mh;
    Mm[4][0][0] = -mh; Mm[4][2][2] = mh;
    double T[3][5][5];
    for (int a = 0; a < 5; a++) for (int b = 0; b < 5; b++) {
        double K[3][3];
        for (int i = 0; i < 3; i++) for (int j = 0; j < 3; j++) {
            double ab = 0, ba = 0;
            for (int r = 0; r < 3; r++) { ab += Mm[a][i][r]*Mm[b][r][j]; ba += Mm[b][i][r]*Mm[a][r][j]; }
            K[i][j] = ab - ba;
        }
        T[0][a][b] = K[1][2]; T[1][a][b] = K[2][0]; T[2][a][b] = K[0][1];
    }

    for (int p = 0; p < 15; p++) {
        int l1 = PL[p][0], l2 = PL[p][1], l3 = PL[p][2];
        int d1 = 2*l1+1, d2 = 2*l2+1, d3 = 2*l3+1, d = d1*d2*d3;
        double tt[125];
        if (((l1 + l2 + l3) & 1) == 0) {
            for (int i = 0; i < d1; i++) for (int j = 0; j < d2; j++) for (int k = 0; k < d3; k++) {
                double a = 0;
                for (int q1 = 0; q1 < nm[l1][i]; q1++)
                for (int q2 = 0; q2 < nm[l2][j]; q2++)
                for (int q3 = 0; q3 < nm[l3][k]; q3++) {
                    const Mono& A = Y[l1][i][q1]; const Mono& B = Y[l2][j][q2]; const Mono& C = Y[l3][k][q3];
                    int xa = A.a+B.a+C.a, yb = A.b+B.b+C.b, zc = A.c+B.c+C.c;
                    if ((xa & 1) || (yb & 1) || (zc & 1)) continue;
                    a += A.co*B.co*C.co * dfact(xa-1)*dfact(yb-1)*dfact(zc-1) / dfact(xa+yb+zc+1);
                }
                tt[(i*d2 + j)*d3 + k] = a;
            }
        } else if (p == 5) {
            for (int q = 0; q < 27; q++) tt[q] = 0;
            tt[0*9+1*3+2] = 1; tt[1*9+2*3+0] = 1; tt[2*9+0*3+1] = 1;
            tt[0*9+2*3+1] = -1; tt[1*9+0*3+2] = -1; tt[2*9+1*3+0] = -1;
        } else {
            for (int q = 0; q < d; q++) tt[q] = 0;
            if (p == 8)  for (int i=0;i<3;i++) for(int a=0;a<5;a++) for(int b=0;b<5;b++) tt[(i*5+a)*5+b] = T[i][a][b];
            if (p == 11) for (int a=0;a<5;a++) for(int i=0;i<3;i++) for(int b=0;b<5;b++) tt[(a*3+i)*5+b] = T[i][a][b];
            if (p == 13) for (int a=0;a<5;a++) for(int b=0;b<5;b++) for(int i=0;i<3;i++) tt[(a*5+b)*3+i] = T[i][a][b];
        }
        double nrm = 0; for (int q = 0; q < d; q++) nrm += tt[q]*tt[q];
        nrm = sqrt(nrm);
        double sg = ((tt[ANCH[p]] >= 0) ? 1.0 : -1.0) * ASGN[p] / nrm;
        for (int q = 0; q < d; q++) w.v[OFF[p] + q] = (float)(tt[q] * sg);
    }
}

// ---------------- device tables (runtime-indexed, ck phase only) ----------------
__device__ const int d_L2r[15]    = {0,1,2,0,1,1,1,2,2,0,1,1,2,2,2};
__device__ const int d_L3r[15]    = {0,1,2,1,0,1,2,1,2,2,1,2,0,1,2};
__device__ const int d_OFFr[15]   = {0,1,10,35,44,53,80,125,170,245,270,315,390,415,490};
__device__ const int d_CKOFFr[15] = {0,1,4,9,18,21,30,45,54,69,94,109,134,139,154};
__device__ const int d_SLOr[3]    = {0,1,4};

#define S_H  0.1414213562373095f    // 1/sqrt(50)
#define S_CS 0.13065629648763766f   // cos(pi/8)/sqrt(50)
#define S_L2 0.03826834323650898f   // sin(pi/8)/10

// packed-weight layout in d_ws (floats) — transposed for u-contiguous b128 loads
#define WS_WP3 0         // [3][50][6][52] {wlin1 l0..2, wsc l0..2} u-major, pad52 -> 46800
#define WS_W6P 46800     // [3][50][3][52] wlin2, u-major, pad52                   -> 23400
#define WS_WGT 70200     // [3][50][52]    Wgate transposed (pad 52)               -> 7800
#define WS_W1T 78000     // [3][100][12]   W1 transposed (pad 12)                  -> 3600
#define WS_W2F 81600     // ushort region: 2 planes (hi,lo) x [3][47][4][64][8]
#define W2F_PLANE 288768 // ushorts per plane
#define WLS_BYTE_OFF 1481472            // 81600*4 + 2*288768*2 (16B aligned)
#define WLS_HALVES   ((size_t)3*40000*752)

__device__ __forceinline__ float sigf(float a) { return 1.0f / (1.0f + expf(-a)); }

__device__ __forceinline__ unsigned bf16_rne(float v) {
    unsigned x = __float_as_uint(v);
    return (x + 0x7FFFu + ((x >> 16) & 1u)) >> 16;
}

#define BUILD_B(KS, BH, BL, TP) { \
    _Pragma("unroll") \
    for (int i_ = 0; i_ < 8; i_++) { \
        float v_ = (TP)[(KS)*32 + (lane >> 4)*8 + i_]; \
        unsigned h_ = bf16_rne(v_); \
        (BH)[i_] = (short)h_; \
        (BL)[i_] = (short)bf16_rne(v_ - __uint_as_float(h_ << 16)); \
    } }

#define TILE_MFMA(KS, BH, BL) { \
    const ushort* ap_ = baseA + (((size_t)tile*4 + (KS))*64 + lane)*8; \
    bf16x8 Ah_ = *(const bf16x8*)ap_; \
    bf16x8 Al_ = *(const bf16x8*)(ap_ + W2F_PLANE); \
    acc = __builtin_amdgcn_mfma_f32_16x16x32_bf16(Ah_, (BH), acc, 0, 0, 0); \
    acc = __builtin_amdgcn_mfma_f32_16x16x32_bf16(Ah_, (BL), acc, 0, 0, 0); \
    acc = __builtin_amdgcn_mfma_f32_16x16x32_bf16(Al_, (BH), acc, 0, 0, 0); }

// packed-FP32 helpers (v_pk_fma_f32 path)
#define LO2(V) __builtin_shufflevector((V), (V), 0, 1)
#define HI2(V) __builtin_shufflevector((V), (V), 2, 3)
#define PKFMA(A, B, C) __builtin_elementwise_fma((A), (B), (C))

// P5 body with compile-time array binding (NO runtime pointer select — rule #20)
#define P5_BODY(HSC, VA) { \
    const __half* whp_ = &wls_h[ea][(VA)*15]; \
    float w_[15]; \
    _Pragma("unroll") \
    for (int p = 0; p < 15; p++) w_[p] = __half2float(whp_[p]); \
    _Pragma("unroll") \
    for (int k = 0; k < 9; ++k) { \
        const int l3 = (k == 0) ? 0 : ((k < 4) ? 1 : 2); \
        const int kl = k - cSLO[l3]; \
        float a_ = 0.f; \
        _Pragma("unroll") \
        for (int pi = cPL3S[l3]; pi < cPL3S[l3+1]; ++pi) { \
            const int p = cPBYL3[pi]; \
            const int l1 = cL1[p]; \
            const int D1 = 2*l1 + 1, D3 = 2*l3 + 1; \
            float mm_ = 0.f; \
            _Pragma("unroll") \
            for (int i = 0; i < D1; ++i) \
                mm_ += ck[ea][cCKOFF[p] + i*D3 + kl] * (HSC)[cSLO[l1] + i]; \
            a_ += w_[p] * mm_; \
        } \
        msg[ea][k*52 + (VA)] = a_ * cINVNP[l3]; \
    } }

// ---------------- one-time weight repack (verified round 10) ----------------
__global__ void k_pack(const float* __restrict__ Wsc, const float* __restrict__ Wlin1,
                       const float* __restrict__ Wlin2, const float* __restrict__ Wgate,
                       const float* __restrict__ W1, const float* __restrict__ W2,
                       float* __restrict__ ws) {
    for (int i = blockIdx.x*blockDim.x + threadIdx.x; i < WS_W2F; i += gridDim.x*blockDim.x) {
        float val = 0.0f;
        if (i < WS_W6P) {                       // WP3T [L][v][c6][u52]
            int u = i % 52, r = i / 52;
            int c = r % 6, v = (r/6) % 50, L = r / 300;
            if (u < 50) {
                if (c < 3) val = Wlin1[L*7500 + c*2500 + u*50 + v];
                else       val = Wsc  [L*7500 + (c-3)*2500 + u*50 + v];
            }
        } else if (i < WS_WGT) {                // W6P [L][v][c3][u52]
            int q = i - WS_W6P;
            int u = q % 52, r = q / 52;
            int c = r % 3, v = (r/3) % 50, L = r / 150;
            if (u < 50) val = Wlin2[L*7500 + c*2500 + u*50 + v];
        } else if (i < WS_W1T) {                // WGT [L][v][u52]
            int q = i - WS_WGT;
            int u = q % 52, v = (q/52) % 50, L = q / 2600;
            if (u < 50) val = Wgate[L*2500 + u*50 + v];
        } else {                                // W1T [L][j][b12]
            int q = i - WS_W1T;
            int b = q % 12, j = (q/12) % 100, L = q / 1200;
            if (b < 10) val = W1[L*1000 + b*100 + j];
        }
        ws[i] = val;
    }
    ushort* w2f = (ushort*)(ws + WS_W2F);
    for (int q = blockIdx.x*blockDim.x + threadIdx.x; q < 2*W2F_PLANE; q += gridDim.x*blockDim.x) {
        int plane = q / W2F_PLANE, r = q % W2F_PLANE;
        int i = r & 7, lane = (r >> 3) & 63, ks = (r >> 9) & 3, tl = r >> 11;
        int tile = tl % 47, L = tl / 47;
        int o = tile*16 + (lane & 15);
        int k = ks*32 + (lane >> 4)*8 + i;
        float w = (k < 100 && o < 750) ? W2[L*75000 + k*750 + o] : 0.0f;
        unsigned h = bf16_rne(w);
        unsigned val;
        if (plane == 0) val = h;
        else {
            float fh = __uint_as_float(h << 16);
            val = bf16_rne(w - fh);
        }
        w2f[q] = (ushort)val;
    }
}

// ---------------- wls precompute (verified rounds 7-15) ----------------
__global__ __launch_bounds__(256, 3) void k_wls(
    const float* __restrict__ node_pos, const float* __restrict__ b1,
    float* __restrict__ ws)
{
    __shared__ __align__(16) float embw[64][12];
    __shared__ __align__(16) float t100s[64][132];
    __shared__ __align__(16) float stage[4][16][20];
    const int t = threadIdx.x;
    const int bid = blockIdx.x;
    const int Lidx = bid / 625;
    const int e0 = (bid % 625) * 64;
    const float* W1T = ws + WS_W1T;
    const ushort* W2F = (const ushort*)(ws + WS_W2F);
    __half* wls_g = (__half*)((char*)ws + WLS_BYTE_OFF);

    if (t < 64) {
        const float* np = node_pos + (size_t)(e0 + t) * 6;
        float vx = np[1] - np[0], vy = np[3] - np[2], vz = np[5] - np[4];
        float r = sqrtf(vx*vx + vy*vy + vz*vz);
        const float step = 4.0f / 11.0f;
        const float RC = (float)(1.14136 * 7.3890560989306495 * 3.1622776601683795);
        #pragma unroll
        for (int b = 0; b < 10; b++) {
            float center = step * (b + 1);
            float diff = (r - center) / step;
            float x1 = diff + 1.0f, x2 = 1.0f - diff;
            float u1 = (x1 > 0.0f) ? expf(-1.0f/x1) : 0.0f;
            float u2 = (x2 > 0.0f) ? expf(-1.0f/x2) : 0.0f;
            embw[t][b] = RC * u1 * u2;
        }
        embw[t][10] = 0.0f; embw[t][11] = 0.0f;
    }
    __syncthreads();

    for (int idx = t; idx < 64*132; idx += 256) {
        int e = idx / 132, j = idx % 132;
        float g = 0.0f;
        if (j < 100) {
            const float* wj = W1T + (Lidx*100 + j)*12;
            float4 wa = *(const float4*)wj;
            float4 wb = *(const float4*)(wj + 4);
            float2 wc = *(const float2*)(wj + 8);
            float4 e0v = *(const float4*)&embw[e][0];
            float4 e1v = *(const float4*)&embw[e][4];
            float2 e2v = *(const float2*)&embw[e][8];
            float a = wa.x*e0v.x + wa.y*e0v.y + wa.z*e0v.z + wa.w*e0v.w
                    + wb.x*e1v.x + wb.y*e1v.y + wb.z*e1v.z + wb.w*e1v.w
                    + wc.x*e2v.x + wc.y*e2v.y;
            a = a * 0.31622776601683794f + b1[Lidx*100 + j];
            float th = tanhf(0.7978845608028654f * (a + 0.044715f * a*a*a));
            g = 0.5f * a * (1.0f + th);
        }
        t100s[e][j] = g;
    }
    __syncthreads();

    const int lane = t & 63, wave = t >> 6;
    const int bcol = lane & 15, bg = lane >> 4;
    const ushort* baseA = W2F + (size_t)Lidx * (47*4*64*8);
    __half* wout = wls_g + (size_t)(Lidx*40000 + e0) * 752;

    for (int eg = 0; eg < 4; eg++) {
        const float* tp = &t100s[eg*16 + bcol][0];
        bf16x8 Bh0, Bh1, Bh2, Bh3, Bl0, Bl1, Bl2, Bl3;
        BUILD_B(0, Bh0, Bl0, tp) BUILD_B(1, Bh1, Bl1, tp)
        BUILD_B(2, Bh2, Bl2, tp) BUILD_B(3, Bh3, Bl3, tp)
        for (int tile = wave; tile < 47; tile += 4) {
            f32x4 acc = {0.f, 0.f, 0.f, 0.f};
            TILE_MFMA(0, Bh0, Bl0) TILE_MFMA(1, Bh1, Bl1)
            TILE_MFMA(2, Bh2, Bl2) TILE_MFMA(3, Bh3, Bl3)
            *(float4*)&stage[wave][bcol][bg*4] = make_float4(acc[0], acc[1], acc[2], acc[3]);
            int er = lane >> 2, o4 = (lane & 3) * 4;
            float4 vv = *(const float4*)&stage[wave][er][o4];
            __half2 p0 = __floats2half2_rn(vv.x * 0.1f, vv.y * 0.1f);
            __half2 p1 = __floats2half2_rn(vv.z * 0.1f, vv.w * 0.1f);
            union { __half2 h2[2]; uint2 u2; } pk;
            pk.h2[0] = p0; pk.h2[1] = p1;
            *(uint2*)(wout + (size_t)(eg*16 + er)*752 + tile*16 + o4) = pk.u2;
        }
    }
}

// ---------------- fused 3-layer kernel: 256 threads, NE=10, VT=2 ----------------
// Round-15's VT=2 savings + restored residency: LDS 78.9 KB -> 2 blocks/CU =
// 8 waves/CU with 4-wave barrier groups. launch_bounds(256,2) -> VGPR cap 256
// (no spill, per round 15's 180-VGPR measurement). act = 250/256 lanes.
__global__ __launch_bounds__(256, 2) void k_fused_pre(
    const float* __restrict__ node_pos, const float* __restrict__ bar,
    const float* __restrict__ Wemb, const float* __restrict__ Wout,
    const float* __restrict__ ws, float* __restrict__ out, W3J w3j)
{
    __shared__ __align__(16) float xs0[NEF][468];      // [m][u52]
    __shared__ __align__(16) float xs1[NEF][468];
    __shared__ __align__(16) float msg[NEF][468];
    __shared__ __align__(16) __half wls_h[NEF][752];
    __shared__ __align__(16) float ck[NEF][180];
    __shared__ __align__(16) float shs[NEF][12];       // 0..8 sh, 9..10 bar pair

    const int t = threadIdx.x;
    const int e0 = blockIdx.x * NEF;

    constexpr int cL1[15]    = {0,0,0,1,1,1,1,1,1,2,2,2,2,2,2};
    constexpr int cCKOFF[15] = {0,1,4,9,18,21,30,45,54,69,94,109,134,139,154};
    constexpr int cSLO[3]    = {0,1,4};
    constexpr int cPBYL3[15] = {0,4,12, 1,3,5,7,10,13, 2,6,8,9,11,14};
    constexpr int cPL3S[4]   = {0,3,9,15};
    constexpr float cINVNP[3] = {0.57735026918962584f, 0.40824829046386302f, 0.40824829046386302f};

    const float* WP3 = ws + WS_WP3;
    const float* W6P = ws + WS_W6P;
    const float* WGT = ws + WS_WGT;
    const __half* wls_g = (const __half*)((const char*)ws + WLS_BYTE_OFF);

    // ---- Phase A: per-edge sh / bar / msg-pad zero (disjoint thread ranges) ----
    if (t < NEF) {
        const int e = t;
        const float* np = node_pos + (size_t)(e0 + e) * 6;
        float vx = np[1] - np[0], vy = np[3] - np[2], vz = np[5] - np[4];
        float r = sqrtf(vx*vx + vy*vy + vz*vz);
        float inv = 1.0f / fmaxf(r, 1e-12f);
        float x = vx*inv, y = vy*inv, z = vz*inv;
        const float s3 = 1.7320508075688772f, s5 = 2.23606797749979f, s15 = 3.872983346207417f;
        shs[e][0] = 1.0f;
        shs[e][1] = s3*x; shs[e][2] = s3*y; shs[e][3] = s3*z;
        shs[e][4] = s15*x*z; shs[e][5] = s15*x*y;
        shs[e][6] = s5*(y*y - 0.5f*(x*x + z*z));
        shs[e][7] = s15*y*z;
        shs[e][8] = 0.5f*s15*(z*z - x*x);
    } else if (t >= 16 && t < 16 + 2*NEF) {
        int q = t - 16;
        shs[q >> 1][9 + (q & 1)] = bar[2*e0 + q];
    } else if (t >= 64 && t < 64 + NEF*18) {
        int q = t - 64;
        int e = q / 18, r = q % 18;
        msg[e][(r >> 1)*52 + 50 + (r & 1)] = 0.0f;
    }
    __syncthreads();

    // ---- Phase B: ck build + x init (transposed, pads zeroed) ----
    for (int idx = t; idx < NEF*179; idx += 256) {
        int e = idx / 179, q = idx % 179;
        int p = 0; while (p < 14 && q >= d_CKOFFr[p+1]) p++;
        int rem = q - d_CKOFFr[p];
        int D2 = 2*d_L2r[p] + 1, D3 = 2*d_L3r[p] + 1;
        int i = rem / D3, k = rem % D3;
        const float* C = w3j.v + d_OFFr[p];
        const float* s = &shs[e][d_SLOr[d_L2r[p]]];
        float a = 0;
        for (int j = 0; j < D2; j++) a += C[(i*D2 + j)*D3 + k] * s[j];
        ck[e][q] = a;
    }
    for (int idx = t; idx < 2*NEF*468; idx += 256) {
        int n = idx / 468, i = idx % 468;
        int e = n >> 1, half = n & 1;
        int m = i / 52, u = i % 52;
        float val = (m == 0 && u < 50) ? shs[e][9 + half] * Wemb[u] : 0.0f;
        if (half) xs1[e][i] = val; else xs0[e][i] = val;
    }
    __syncthreads();

    const bool act = (t < 25*NEF);          // 250 threads
    const int v = t / NEF, ea = t % NEF;    // v in [0,25); handles v and v+25

    // ================== 3 layers, all in LDS ==================
    for (int L = 0; L < 3; L++) {
        // ---- wls global->LDS raw fp16 copy; hides under P3 ----
        {
            const __half* wsrc = wls_g + (size_t)(L*40000 + e0) * 752;
            for (int idx = t; idx < NEF*94; idx += 256) {
                int e = idx / 94, c = idx % 94;
                *(uint4*)&wls_h[e][c*8] = *(const uint4*)(wsrc + (size_t)e*752 + c*8);
            }
        }

        // ---- P3: three lmixes; VT=2, packed-FP32 ----
        f32x2 hA[9], nA[9], mA[9];   // v:     hsc, n0r, n1r
        f32x2 hB[9], nB[9], mB[9];   // v+25
        #pragma unroll
        for (int m = 0; m < 9; m++) {
            hA[m] = (f32x2){0.f,0.f}; nA[m] = (f32x2){0.f,0.f}; mA[m] = (f32x2){0.f,0.f};
            hB[m] = (f32x2){0.f,0.f}; nB[m] = (f32x2){0.f,0.f}; mB[m] = (f32x2){0.f,0.f};
        }
        if (act) {
            const float* wpA = WP3 + (size_t)(L*50 + v) * 312;        // [c6][u52]
            const float* wpB = WP3 + (size_t)(L*50 + v + 25) * 312;
            for (int u4 = 0; u4 < 52; u4 += 4) {
                f32x4 q[9];
                #pragma unroll
                for (int m = 0; m < 9; m++) q[m] = *(const f32x4*)&xs0[ea][m*52 + u4];
                f32x4 sA0 = *(const f32x4*)(wpA + 156 + u4);
                f32x4 sA1 = *(const f32x4*)(wpA + 208 + u4);
                f32x4 sA2 = *(const f32x4*)(wpA + 260 + u4);
                f32x4 sB0 = *(const f32x4*)(wpB + 156 + u4);
                f32x4 sB1 = *(const f32x4*)(wpB + 208 + u4);
                f32x4 sB2 = *(const f32x4*)(wpB + 260 + u4);
                {   // v (A): Wlin1 transient
                    f32x4 l0 = *(const f32x4*)(wpA + 0 + u4);
                    f32x4 l1 = *(const f32x4*)(wpA + 52 + u4);
                    f32x4 l2 = *(const f32x4*)(wpA + 104 + u4);
                    #pragma unroll
                    for (int m = 0; m < 9; m++) {
                        const int l = (m == 0) ? 0 : ((m < 4) ? 1 : 2);
                        const f32x4 wl = (l==0) ? l0 : ((l==1) ? l1 : l2);
                        const f32x4 wv = (l==0) ? sA0 : ((l==1) ? sA1 : sA2);
                        hA[m] = PKFMA(LO2(q[m]), LO2(wl), hA[m]);
                        hA[m] = PKFMA(HI2(q[m]), HI2(wl), hA[m]);
                        nA[m] = PKFMA(LO2(q[m]), LO2(wv), nA[m]);
                        nA[m] = PKFMA(HI2(q[m]), HI2(wv), nA[m]);
                    }
                }
                {   // v+25 (B)
                    f32x4 l0 = *(const f32x4*)(wpB + 0 + u4);
                    f32x4 l1 = *(const f32x4*)(wpB + 52 + u4);
                    f32x4 l2 = *(const f32x4*)(wpB + 104 + u4);
                    #pragma unroll
                    for (int m = 0; m < 9; m++) {
                        const int l = (m == 0) ? 0 : ((m < 4) ? 1 : 2);
                        const f32x4 wl = (l==0) ? l0 : ((l==1) ? l1 : l2);
                        const f32x4 wv = (l==0) ? sB0 : ((l==1) ? sB1 : sB2);
                        hB[m] = PKFMA(LO2(q[m]), LO2(wl), hB[m]);
                        hB[m] = PKFMA(HI2(q[m]), HI2(wl), hB[m]);
                        nB[m] = PKFMA(LO2(q[m]), LO2(wv), nB[m]);
                        nB[m] = PKFMA(HI2(q[m]), HI2(wv), nB[m]);
                    }
                }
                // xs1 half: n1r for both v (Wsc still live)
                #pragma unroll
                for (int m = 0; m < 9; m++) q[m] = *(const f32x4*)&xs1[ea][m*52 + u4];
                #pragma unroll
                for (int m = 0; m < 9; m++) {
                    const int l = (m == 0) ? 0 : ((m < 4) ? 1 : 2);
                    const f32x4 wvA = (l==0) ? sA0 : ((l==1) ? sA1 : sA2);
                    const f32x4 wvB = (l==0) ? sB0 : ((l==1) ? sB1 : sB2);
                    mA[m] = PKFMA(LO2(q[m]), LO2(wvA), mA[m]);
                    mA[m] = PKFMA(HI2(q[m]), HI2(wvA), mA[m]);
                    mB[m] = PKFMA(LO2(q[m]), LO2(wvB), mB[m]);
                    mB[m] = PKFMA(HI2(q[m]), HI2(wvB), mB[m]);
                }
            }
        }
        float hscA[9], hscB[9];
        #pragma unroll
        for (int m = 0; m < 9; m++) {
            hscA[m] = (hA[m].x + hA[m].y) * S_H;
            hscB[m] = (hB[m].x + hB[m].y) * S_H;
        }
        __syncthreads();   // A: xs reads done; wls_h copy settled

        if (act) {
            #pragma unroll
            for (int m = 0; m < 9; m++) {
                xs0[ea][m*52 + v]      = (nA[m].x + nA[m].y) * S_CS;
                xs1[ea][m*52 + v]      = (mA[m].x + mA[m].y) * S_CS;
                xs0[ea][m*52 + v + 25] = (nB[m].x + nB[m].y) * S_CS;
                xs1[ea][m*52 + v + 25] = (mB[m].x + mB[m].y) * S_CS;
            }
        }
        __syncthreads();   // B

        // ---- P5: tensor-product messages (expanded twice, compile-time arrays) ----
        if (act) {
            P5_BODY(hscA, v)
            P5_BODY(hscB, v + 25)
        }
        __syncthreads();   // C

        // ---- P6: xs1 += lmix(msg, Wlin2) * S_L2; VT=2, packed-FP32 ----
        if (act) {
            const float* w6A = W6P + (size_t)(L*50 + v) * 156;        // [c3][u52]
            const float* w6B = W6P + (size_t)(L*50 + v + 25) * 156;
            f32x2 aA[9], aB[9];
            #pragma unroll
            for (int m = 0; m < 9; m++) { aA[m] = (f32x2){0.f,0.f}; aB[m] = (f32x2){0.f,0.f}; }
            for (int u4 = 0; u4 < 52; u4 += 4) {
                f32x4 q[9];
                #pragma unroll
                for (int m = 0; m < 9; m++) q[m] = *(const f32x4*)&msg[ea][m*52 + u4];
                f32x4 wA0 = *(const f32x4*)(w6A +   0 + u4);
                f32x4 wA1 = *(const f32x4*)(w6A +  52 + u4);
                f32x4 wA2 = *(const f32x4*)(w6A + 104 + u4);
                f32x4 wB0 = *(const f32x4*)(w6B +   0 + u4);
                f32x4 wB1 = *(const f32x4*)(w6B +  52 + u4);
                f32x4 wB2 = *(const f32x4*)(w6B + 104 + u4);
                #pragma unroll
                for (int m = 0; m < 9; m++) {
                    const int l = (m == 0) ? 0 : ((m < 4) ? 1 : 2);
                    const f32x4 wvA = (l==0) ? wA0 : ((l==1) ? wA1 : wA2);
                    const f32x4 wvB = (l==0) ? wB0 : ((l==1) ? wB1 : wB2);
                    aA[m] = PKFMA(LO2(q[m]), LO2(wvA), aA[m]);
                    aA[m] = PKFMA(HI2(q[m]), HI2(wvA), aA[m]);
                    aB[m] = PKFMA(LO2(q[m]), LO2(wvB), aB[m]);
                    aB[m] = PKFMA(HI2(q[m]), HI2(wvB), aB[m]);
                }
            }
            #pragma unroll
            for (int m = 0; m < 9; m++) {
                xs1[ea][m*52 + v]      += (aA[m].x + aA[m].y) * S_L2;
                xs1[ea][m*52 + v + 25] += (aB[m].x + aB[m].y) * S_L2;
            }
        }
        __syncthreads();   // D

        // ---- P7: gate matmuls -> REGISTERS; VT=2 ----
        float g0A = 0.f, g1A = 0.f, g0B = 0.f, g1B = 0.f;
        if (act) {
            const float* wgA = WGT + (L*50 + v) * 52;
            const float* wgB = WGT + (L*50 + v + 25) * 52;
            f32x2 a0A = (f32x2){0.f,0.f}, a1A = (f32x2){0.f,0.f};
            f32x2 a0B = (f32x2){0.f,0.f}, a1B = (f32x2){0.f,0.f};
            #pragma unroll
            for (int u4 = 0; u4 < 52; u4 += 4) {
                f32x4 x0 = *(const f32x4*)&xs0[ea][u4];   // m=0 row
                f32x4 x1 = *(const f32x4*)&xs1[ea][u4];
                f32x4 wA = *(const f32x4*)(wgA + u4);
                f32x4 wB = *(const f32x4*)(wgB + u4);
                a0A = PKFMA(LO2(x0), LO2(wA), a0A); a0A = PKFMA(HI2(x0), HI2(wA), a0A);
                a1A = PKFMA(LO2(x1), LO2(wA), a1A); a1A = PKFMA(HI2(x1), HI2(wA), a1A);
                a0B = PKFMA(LO2(x0), LO2(wB), a0B); a0B = PKFMA(HI2(x0), HI2(wB), a0B);
                a1B = PKFMA(LO2(x1), LO2(wB), a1B); a1B = PKFMA(HI2(x1), HI2(wB), a1B);
            }
            g0A = sigf((a0A.x + a0A.y) * S_H);
            g1A = sigf((a1A.x + a1A.y) * S_H);
            g0B = sigf((a0B.x + a0B.y) * S_H);
            g1B = sigf((a1B.x + a1B.y) * S_H);
        }
        __syncthreads();   // E: all P7 xs reads done before P8 writes

        // ---- P8: gate apply, act-owned, both columns ----
        if (act) {
            {
                float* p0 = &xs0[ea][v];
                float* p1 = &xs1[ea][v];
                float s0 = p0[0], s1 = p1[0];
                p0[0] = s0 * sigf(s0);
                p1[0] = s1 * sigf(s1);
                #pragma unroll
                for (int m = 1; m < 9; m++) { p0[m*52] *= g0A; p1[m*52] *= g1A; }
            }
            {
                float* p0 = &xs0[ea][v + 25];
                float* p1 = &xs1[ea][v + 25];
                float s0 = p0[0], s1 = p1[0];
                p0[0] = s0 * sigf(s0);
                p1[0] = s1 * sigf(s1);
                #pragma unroll
                for (int m = 1; m < 9; m++) { p0[m*52] *= g0B; p1[m*52] *= g1B; }
            }
        }
        __syncthreads();   // F
    }

    // ---- Output projection: rows (1+m) are u-contiguous ----
    if (t < NEF*6) {
        int e = t / 6, r = t % 6, half = r / 3, m = r % 3;
        const float* xp = half ? &xs1[e][(1 + m)*52] : &xs0[e][(1 + m)*52];
        float a = 0;
        #pragma unroll 2
        for (int u = 0; u < 50; ++u) a += xp[u] * Wout[u];
        out[((size_t)(2*(e0 + e) + half))*3 + m] = a * S_H;
    }
}

// ---------------- launch ----------------
extern "C" void kernel_launch(void* const* d_in, const int* in_sizes, int n_in,
                              void* d_out, int out_size, void* d_ws, size_t ws_size,
                              hipStream_t stream) {
    const float* node_pos = (const float*)d_in[0];
    const float* bar      = (const float*)d_in[1];
    const float* Wemb     = (const float*)d_in[2];
    const float* Wsc      = (const float*)d_in[3];
    const float* Wlin1    = (const float*)d_in[4];
    const float* W1       = (const float*)d_in[5];
    const float* b1       = (const float*)d_in[6];
    const float* W2       = (const float*)d_in[7];
    const float* Wlin2    = (const float*)d_in[8];
    const float* Wgate    = (const float*)d_in[9];
    const float* Wout     = (const float*)d_in[10];
    float* out = (float*)d_out;
    float* ws  = (float*)d_ws;

    W3J w3j;
    build_w3j(w3j);

    k_pack<<<1024, 256, 0, stream>>>(Wsc, Wlin1, Wlin2, Wgate, W1, W2, ws);
    k_wls<<<1875, 256, 0, stream>>>(node_pos, b1, ws);
    k_fused_pre<<<E_EDGES/NEF, 256, 0, stream>>>(node_pos, bar, Wemb, Wout, ws, out, w3j);
}

// Round 17
// 803.348 us; speedup vs baseline: 1.4523x; 1.4523x over previous
//
#include <hip/hip_runtime.h>
#include <hip/hip_fp16.h>
#include <math.h>
#include <string.h>

// ---------------- problem constants ----------------
#define E_EDGES 40000
#define N_NODES 80000
#define NE5 5         // edges per block

// ---- sign knobs (verified correct in round 1) ----
#define S111 1.0
#define S122 1.0
#define S212 1.0
#define S221 1.0
#define S222 1.0

struct W3J { float v[615]; };

typedef __attribute__((ext_vector_type(8))) short bf16x8;
typedef __attribute__((ext_vector_type(4))) float f32x4;
typedef __attribute__((ext_vector_type(2))) float f32x2;

// ---------------- host: build W3J tensors (verified round 1) ----------------
static void build_w3j(W3J& w) {
    const double s3 = sqrt(3.0), s5 = sqrt(5.0), s15 = sqrt(15.0);
    struct Mono { int a, b, c; double co; };
    Mono Y[3][5][3]; int nm[3][5];
    for (int l = 0; l < 3; l++) for (int c = 0; c < 5; c++) nm[l][c] = 0;
    nm[0][0] = 1; Y[0][0][0] = Mono{0,0,0,1.0};
    nm[1][0] = 1; Y[1][0][0] = Mono{1,0,0,s3};
    nm[1][1] = 1; Y[1][1][0] = Mono{0,1,0,s3};
    nm[1][2] = 1; Y[1][2][0] = Mono{0,0,1,s3};
    nm[2][0] = 1; Y[2][0][0] = Mono{1,0,1,s15};
    nm[2][1] = 1; Y[2][1][0] = Mono{1,1,0,s15};
    nm[2][2] = 3; Y[2][2][0] = Mono{0,2,0,s5};  Y[2][2][1] = Mono{2,0,0,-0.5*s5}; Y[2][2][2] = Mono{0,0,2,-0.5*s5};
    nm[2][3] = 1; Y[2][3][0] = Mono{0,1,1,s15};
    nm[2][4] = 2; Y[2][4][0] = Mono{0,0,2,0.5*s15}; Y[2][4][1] = Mono{2,0,0,-0.5*s15};

    static const int PL[15][3] = {{0,0,0},{0,1,1},{0,2,2},{1,0,1},{1,1,0},{1,1,1},{1,1,2},{1,2,1},
                                  {1,2,2},{2,0,2},{2,1,1},{2,1,2},{2,2,0},{2,2,1},{2,2,2}};
    static const int OFF[15]  = {0,1,10,35,44,53,80,125,170,245,270,315,390,415,490};
    static const int ANCH[15] = {0,0,0,0,0,5,22,22,29,0,22,9,0,13,2};
    const double ASGN[15] = {1,1,1,1,1, S111, 1,1, S122, 1,1, S212, 1, S221, S222};

    auto dfact = [](int n) { double r = 1.0; for (int k = n; k > 1; k -= 2) r *= k; return r; };

    double Mm[5][3][3]; memset(Mm, 0, sizeof(Mm));
    const double mh = s15 * 0.5;
    Mm[0][0][2] = Mm[0][2][0] = mh;
    Mm[1][0][1] = Mm[1][1][0] = mh;
    Mm[2][0][0] = -0.5*s5; Mm[2][1][1] = s5; Mm[2][2][2] = -0.5*s5;
    Mm[3][1][2] = Mm[3][2][1] = mh;
    Mm[4][0][0] = -mh; Mm[4][2][2] = mh;
    double T[3][5][5];
    for (int a = 0; a < 5; a++) for (int b = 0; b < 5; b++) {
        double K[3][3];
        for (int i = 0; i < 3; i++) for (int j = 0; j < 3; j++) {
            double ab = 0, ba = 0;
            for (int r = 0; r < 3; r++) { ab += Mm[a][i][r]*Mm[b][r][j]; ba += Mm[b][i][r]*Mm[a][r][j]; }
            K[i][j] = ab - ba;
        }
        T[0][a][b] = K[1][2]; T[1][a][b] = K[2][0]; T[2][a][b] = K[0][1];
    }

    for (int p = 0; p < 15; p++) {
        int l1 = PL[p][0], l2 = PL[p][1], l3 = PL[p][2];
        int d1 = 2*l1+1, d2 = 2*l2+1, d3 = 2*l3+1, d = d1*d2*d3;
        double tt[125];
        if (((l1 + l2 + l3) & 1) == 0) {
            for (int i = 0; i < d1; i++) for (int j = 0; j < d2; j++) for (int k = 0; k < d3; k++) {
                double a = 0;
                for (int q1 = 0; q1 < nm[l1][i]; q1++)
                for (int q2 = 0; q2 < nm[l2][j]; q2++)
                for (int q3 = 0; q3 < nm[l3][k]; q3++) {
                    const Mono& A = Y[l1][i][q1]; const Mono& B = Y[l2][j][q2]; const Mono& C = Y[l3][k][q3];
                    int xa = A.a+B.a+C.a, yb = A.b+B.b+C.b, zc = A.c+B.c+C.c;
                    if ((xa & 1) || (yb & 1) || (zc & 1)) continue;
                    a += A.co*B.co*C.co * dfact(xa-1)*dfact(yb-1)*dfact(zc-1) / dfact(xa+yb+zc+1);
                }
                tt[(i*d2 + j)*d3 + k] = a;
            }
        } else if (p == 5) {
            for (int q = 0; q < 27; q++) tt[q] = 0;
            tt[0*9+1*3+2] = 1; tt[1*9+2*3+0] = 1; tt[2*9+0*3+1] = 1;
            tt[0*9+2*3+1] = -1; tt[1*9+0*3+2] = -1; tt[2*9+1*3+0] = -1;
        } else {
            for (int q = 0; q < d; q++) tt[q] = 0;
            if (p == 8)  for (int i=0;i<3;i++) for(int a=0;a<5;a++) for(int b=0;b<5;b++) tt[(i*5+a)*5+b] = T[i][a][b];
            if (p == 11) for (int a=0;a<5;a++) for(int i=0;i<3;i++) for(int b=0;b<5;b++) tt[(a*3+i)*5+b] = T[i][a][b];
            if (p == 13) for (int a=0;a<5;a++) for(int b=0;b<5;b++) for(int i=0;i<3;i++) tt[(a*5+b)*3+i] = T[i][a][b];
        }
        double nrm = 0; for (int q = 0; q < d; q++) nrm += tt[q]*tt[q];
        nrm = sqrt(nrm);
        double sg = ((tt[ANCH[p]] >= 0) ? 1.0 : -1.0) * ASGN[p] / nrm;
        for (int q = 0; q < d; q++) w.v[OFF[p] + q] = (float)(tt[q] * sg);
    }
}

// ---------------- device tables (runtime-indexed, ck phase only) ----------------
__device__ const int d_L2r[15]    = {0,1,2,0,1,1,1,2,2,0,1,1,2,2,2};
__device__ const int d_L3r[15]    = {0,1,2,1,0,1,2,1,2,2,1,2,0,1,2};
__device__ const int d_OFFr[15]   = {0,1,10,35,44,53,80,125,170,245,270,315,390,415,490};
__device__ const int d_CKOFFr[15] = {0,1,4,9,18,21,30,45,54,69,94,109,134,139,154};
__device__ const int d_SLOr[3]    = {0,1,4};

#define S_H  0.1414213562373095f    // 1/sqrt(50)
#define S_CS 0.13065629648763766f   // cos(pi/8)/sqrt(50)
#define S_L2 0.03826834323650898f   // sin(pi/8)/10

// packed-weight layout in d_ws (floats) — transposed for u-contiguous b128 loads
#define WS_WP3 0         // [3][50][6][52] {wlin1 l0..2, wsc l0..2} u-major, pad52 -> 46800
#define WS_W6P 46800     // [3][50][3][52] wlin2, u-major, pad52                   -> 23400
#define WS_WGT 70200     // [3][50][52]    Wgate transposed (pad 52)               -> 7800
#define WS_W1T 78000     // [3][100][12]   W1 transposed (pad 12)                  -> 3600
#define WS_W2F 81600     // ushort region: 2 planes (hi,lo) x [3][47][4][64][8]
#define W2F_PLANE 288768 // ushorts per plane
#define WLS_BYTE_OFF 1481472            // 81600*4 + 2*288768*2 (16B aligned)
#define WLS_HALVES   ((size_t)3*40000*752)

__device__ __forceinline__ float sigf(float a) { return 1.0f / (1.0f + expf(-a)); }

__device__ __forceinline__ unsigned bf16_rne(float v) {
    unsigned x = __float_as_uint(v);
    return (x + 0x7FFFu + ((x >> 16) & 1u)) >> 16;
}

#define BUILD_B(KS, BH, BL, TP) { \
    _Pragma("unroll") \
    for (int i_ = 0; i_ < 8; i_++) { \
        float v_ = (TP)[(KS)*32 + (lane >> 4)*8 + i_]; \
        unsigned h_ = bf16_rne(v_); \
        (BH)[i_] = (short)h_; \
        (BL)[i_] = (short)bf16_rne(v_ - __uint_as_float(h_ << 16)); \
    } }

#define TILE_MFMA(KS, BH, BL) { \
    const ushort* ap_ = baseA + (((size_t)tile*4 + (KS))*64 + lane)*8; \
    bf16x8 Ah_ = *(const bf16x8*)ap_; \
    bf16x8 Al_ = *(const bf16x8*)(ap_ + W2F_PLANE); \
    acc = __builtin_amdgcn_mfma_f32_16x16x32_bf16(Ah_, (BH), acc, 0, 0, 0); \
    acc = __builtin_amdgcn_mfma_f32_16x16x32_bf16(Ah_, (BL), acc, 0, 0, 0); \
    acc = __builtin_amdgcn_mfma_f32_16x16x32_bf16(Al_, (BH), acc, 0, 0, 0); }

// packed-FP32 helpers (v_pk_fma_f32 path)
#define LO2(V) __builtin_shufflevector((V), (V), 0, 1)
#define HI2(V) __builtin_shufflevector((V), (V), 2, 3)
#define PKFMA(A, B, C) __builtin_elementwise_fma((A), (B), (C))

// ---------------- one-time weight repack (verified round 10) ----------------
__global__ void k_pack(const float* __restrict__ Wsc, const float* __restrict__ Wlin1,
                       const float* __restrict__ Wlin2, const float* __restrict__ Wgate,
                       const float* __restrict__ W1, const float* __restrict__ W2,
                       float* __restrict__ ws) {
    for (int i = blockIdx.x*blockDim.x + threadIdx.x; i < WS_W2F; i += gridDim.x*blockDim.x) {
        float val = 0.0f;
        if (i < WS_W6P) {                       // WP3T [L][v][c6][u52]
            int u = i % 52, r = i / 52;
            int c = r % 6, v = (r/6) % 50, L = r / 300;
            if (u < 50) {
                if (c < 3) val = Wlin1[L*7500 + c*2500 + u*50 + v];
                else       val = Wsc  [L*7500 + (c-3)*2500 + u*50 + v];
            }
        } else if (i < WS_WGT) {                // W6P [L][v][c3][u52]
            int q = i - WS_W6P;
            int u = q % 52, r = q / 52;
            int c = r % 3, v = (r/3) % 50, L = r / 150;
            if (u < 50) val = Wlin2[L*7500 + c*2500 + u*50 + v];
        } else if (i < WS_W1T) {                // WGT [L][v][u52]
            int q = i - WS_WGT;
            int u = q % 52, v = (q/52) % 50, L = q / 2600;
            if (u < 50) val = Wgate[L*2500 + u*50 + v];
        } else {                                // W1T [L][j][b12]
            int q = i - WS_W1T;
            int b = q % 12, j = (q/12) % 100, L = q / 1200;
            if (b < 10) val = W1[L*1000 + b*100 + j];
        }
        ws[i] = val;
    }
    ushort* w2f = (ushort*)(ws + WS_W2F);
    for (int q = blockIdx.x*blockDim.x + threadIdx.x; q < 2*W2F_PLANE; q += gridDim.x*blockDim.x) {
        int plane = q / W2F_PLANE, r = q % W2F_PLANE;
        int i = r & 7, lane = (r >> 3) & 63, ks = (r >> 9) & 3, tl = r >> 11;
        int tile = tl % 47, L = tl / 47;
        int o = tile*16 + (lane & 15);
        int k = ks*32 + (lane >> 4)*8 + i;
        float w = (k < 100 && o < 750) ? W2[L*75000 + k*750 + o] : 0.0f;
        unsigned h = bf16_rne(w);
        unsigned val;
        if (plane == 0) val = h;
        else {
            float fh = __uint_as_float(h << 16);
            val = bf16_rne(w - fh);
        }
        w2f[q] = (ushort)val;
    }
}

// ---------------- wls precompute (verified rounds 7-16) ----------------
__global__ __launch_bounds__(256, 3) void k_wls(
    const float* __restrict__ node_pos, const float* __restrict__ b1,
    float* __restrict__ ws)
{
    __shared__ __align__(16) float embw[64][12];
    __shared__ __align__(16) float t100s[64][132];
    __shared__ __align__(16) float stage[4][16][20];
    const int t = threadIdx.x;
    const int bid = blockIdx.x;
    const int Lidx = bid / 625;
    const int e0 = (bid % 625) * 64;
    const float* W1T = ws + WS_W1T;
    const ushort* W2F = (const ushort*)(ws + WS_W2F);
    __half* wls_g = (__half*)((char*)ws + WLS_BYTE_OFF);

    if (t < 64) {
        const float* np = node_pos + (size_t)(e0 + t) * 6;
        float vx = np[1] - np[0], vy = np[3] - np[2], vz = np[5] - np[4];
        float r = sqrtf(vx*vx + vy*vy + vz*vz);
        const float step = 4.0f / 11.0f;
        const float RC = (float)(1.14136 * 7.3890560989306495 * 3.1622776601683795);
        #pragma unroll
        for (int b = 0; b < 10; b++) {
            float center = step * (b + 1);
            float diff = (r - center) / step;
            float x1 = diff + 1.0f, x2 = 1.0f - diff;
            float u1 = (x1 > 0.0f) ? expf(-1.0f/x1) : 0.0f;
            float u2 = (x2 > 0.0f) ? expf(-1.0f/x2) : 0.0f;
            embw[t][b] = RC * u1 * u2;
        }
        embw[t][10] = 0.0f; embw[t][11] = 0.0f;
    }
    __syncthreads();

    for (int idx = t; idx < 64*132; idx += 256) {
        int e = idx / 132, j = idx % 132;
        float g = 0.0f;
        if (j < 100) {
            const float* wj = W1T + (Lidx*100 + j)*12;
            float4 wa = *(const float4*)wj;
            float4 wb = *(const float4*)(wj + 4);
            float2 wc = *(const float2*)(wj + 8);
            float4 e0v = *(const float4*)&embw[e][0];
            float4 e1v = *(const float4*)&embw[e][4];
            float2 e2v = *(const float2*)&embw[e][8];
            float a = wa.x*e0v.x + wa.y*e0v.y + wa.z*e0v.z + wa.w*e0v.w
                    + wb.x*e1v.x + wb.y*e1v.y + wb.z*e1v.z + wb.w*e1v.w
                    + wc.x*e2v.x + wc.y*e2v.y;
            a = a * 0.31622776601683794f + b1[Lidx*100 + j];
            float th = tanhf(0.7978845608028654f * (a + 0.044715f * a*a*a));
            g = 0.5f * a * (1.0f + th);
        }
        t100s[e][j] = g;
    }
    __syncthreads();

    const int lane = t & 63, wave = t >> 6;
    const int bcol = lane & 15, bg = lane >> 4;
    const ushort* baseA = W2F + (size_t)Lidx * (47*4*64*8);
    __half* wout = wls_g + (size_t)(Lidx*40000 + e0) * 752;

    for (int eg = 0; eg < 4; eg++) {
        const float* tp = &t100s[eg*16 + bcol][0];
        bf16x8 Bh0, Bh1, Bh2, Bh3, Bl0, Bl1, Bl2, Bl3;
        BUILD_B(0, Bh0, Bl0, tp) BUILD_B(1, Bh1, Bl1, tp)
        BUILD_B(2, Bh2, Bl2, tp) BUILD_B(3, Bh3, Bl3, tp)
        for (int tile = wave; tile < 47; tile += 4) {
            f32x4 acc = {0.f, 0.f, 0.f, 0.f};
            TILE_MFMA(0, Bh0, Bl0) TILE_MFMA(1, Bh1, Bl1)
            TILE_MFMA(2, Bh2, Bl2) TILE_MFMA(3, Bh3, Bl3)
            *(float4*)&stage[wave][bcol][bg*4] = make_float4(acc[0], acc[1], acc[2], acc[3]);
            int er = lane >> 2, o4 = (lane & 3) * 4;
            float4 vv = *(const float4*)&stage[wave][er][o4];
            __half2 p0 = __floats2half2_rn(vv.x * 0.1f, vv.y * 0.1f);
            __half2 p1 = __floats2half2_rn(vv.z * 0.1f, vv.w * 0.1f);
            union { __half2 h2[2]; uint2 u2; } pk;
            pk.h2[0] = p0; pk.h2[1] = p1;
            *(uint2*)(wout + (size_t)(eg*16 + er)*752 + tile*16 + o4) = pk.u2;
        }
    }
}

// ---------------- fused 3-layer kernel (round-11 verified best: 705 us) ----------------
// NE=5, 256 threads, [m][u52] transposed state, packed-FP32 (v_pk_fma_f32) math.
// VGPR 64 at launch_bounds(256,4); 4 blocks/CU (16 waves). act = 250/256 lanes.
__global__ __launch_bounds__(256, 4) void k_fused_pre(
    const float* __restrict__ node_pos, const float* __restrict__ bar,
    const float* __restrict__ Wemb, const float* __restrict__ Wout,
    const float* __restrict__ ws, float* __restrict__ out, W3J w3j)
{
    __shared__ __align__(16) float xs0[NE5][468];      // [m][u52]
    __shared__ __align__(16) float xs1[NE5][468];
    __shared__ __align__(16) float msg[NE5][468];
    __shared__ __align__(16) __half wls_h[NE5][752];
    __shared__ __align__(16) float ck[NE5][180];
    __shared__ __align__(16) float shs[NE5][12];       // 0..8 sh, 9..10 bar pair

    const int t = threadIdx.x;
    const int e0 = blockIdx.x * NE5;

    constexpr int cL1[15]    = {0,0,0,1,1,1,1,1,1,2,2,2,2,2,2};
    constexpr int cCKOFF[15] = {0,1,4,9,18,21,30,45,54,69,94,109,134,139,154};
    constexpr int cSLO[3]    = {0,1,4};
    constexpr int cPBYL3[15] = {0,4,12, 1,3,5,7,10,13, 2,6,8,9,11,14};
    constexpr int cPL3S[4]   = {0,3,9,15};
    constexpr float cINVNP[3] = {0.57735026918962584f, 0.40824829046386302f, 0.40824829046386302f};

    const float* WP3 = ws + WS_WP3;
    const float* W6P = ws + WS_W6P;
    const float* WGT = ws + WS_WGT;
    const __half* wls_g = (const __half*)((const char*)ws + WLS_BYTE_OFF);

    // ---- Phase A: per-edge sh ----
    if (t < NE5) {
        const int e = t;
        const float* np = node_pos + (size_t)(e0 + e) * 6;
        float vx = np[1] - np[0], vy = np[3] - np[2], vz = np[5] - np[4];
        float r = sqrtf(vx*vx + vy*vy + vz*vz);
        float inv = 1.0f / fmaxf(r, 1e-12f);
        float x = vx*inv, y = vy*inv, z = vz*inv;
        const float s3 = 1.7320508075688772f, s5 = 2.23606797749979f, s15 = 3.872983346207417f;
        shs[e][0] = 1.0f;
        shs[e][1] = s3*x; shs[e][2] = s3*y; shs[e][3] = s3*z;
        shs[e][4] = s15*x*z; shs[e][5] = s15*x*y;
        shs[e][6] = s5*(y*y - 0.5f*(x*x + z*z));
        shs[e][7] = s15*y*z;
        shs[e][8] = 0.5f*s15*(z*z - x*x);
    }
    if (t >= 64 && t < 64 + 2*NE5) {
        int q = t - 64;
        shs[q >> 1][9 + (q & 1)] = bar[2*e0 + q];
    }
    // zero msg pad columns (u=50,51) once
    if (t >= 128 && t < 128 + NE5*18) {
        int q = t - 128;
        int e = q / 18, r = q % 18;
        msg[e][(r >> 1)*52 + 50 + (r & 1)] = 0.0f;
    }
    __syncthreads();

    // ---- Phase B: ck build + x init (transposed, pads zeroed) ----
    for (int idx = t; idx < NE5*179; idx += 256) {
        int e = idx / 179, q = idx % 179;
        int p = 0; while (p < 14 && q >= d_CKOFFr[p+1]) p++;
        int rem = q - d_CKOFFr[p];
        int D2 = 2*d_L2r[p] + 1, D3 = 2*d_L3r[p] + 1;
        int i = rem / D3, k = rem % D3;
        const float* C = w3j.v + d_OFFr[p];
        const float* s = &shs[e][d_SLOr[d_L2r[p]]];
        float a = 0;
        for (int j = 0; j < D2; j++) a += C[(i*D2 + j)*D3 + k] * s[j];
        ck[e][q] = a;
    }
    for (int idx = t; idx < 2*NE5*468; idx += 256) {
        int n = idx / 468, i = idx % 468;
        int e = n >> 1, half = n & 1;
        int m = i / 52, u = i % 52;
        float val = (m == 0 && u < 50) ? shs[e][9 + half] * Wemb[u] : 0.0f;
        if (half) xs1[e][i] = val; else xs0[e][i] = val;
    }
    __syncthreads();

    const bool act = (t < 50*NE5);
    const int v = t / NE5, ea = t % NE5;

    // ================== 3 layers, all in LDS ==================
    for (int L = 0; L < 3; L++) {
        // ---- wls global->LDS raw fp16 copy; hides under P3 ----
        {
            const __half* wsrc = wls_g + (size_t)(L*40000 + e0) * 752;
            for (int idx = t; idx < NE5*94; idx += 256) {
                int e = idx / 94, c = idx % 94;
                *(uint4*)&wls_h[e][c*8] = *(const uint4*)(wsrc + (size_t)e*752 + c*8);
            }
        }

        // ---- P3: three lmixes; packed-FP32 accumulation (v_pk_fma_f32) ----
        f32x2 hsc2[9], n0r2[9], n1r2[9];
        #pragma unroll
        for (int m = 0; m < 9; m++) {
            hsc2[m] = (f32x2){0.f, 0.f};
            n0r2[m] = (f32x2){0.f, 0.f};
            n1r2[m] = (f32x2){0.f, 0.f};
        }
        if (act) {
            const float* wp = WP3 + (size_t)(L*50 + v) * 312;   // [c6][u52]
            for (int u4 = 0; u4 < 52; u4 += 4) {
                f32x4 wl0 = *(const f32x4*)(wp +   0 + u4);
                f32x4 wl1 = *(const f32x4*)(wp +  52 + u4);
                f32x4 wl2 = *(const f32x4*)(wp + 104 + u4);
                f32x4 ws0 = *(const f32x4*)(wp + 156 + u4);
                f32x4 ws1 = *(const f32x4*)(wp + 208 + u4);
                f32x4 ws2 = *(const f32x4*)(wp + 260 + u4);
                f32x4 q[9];
                #pragma unroll
                for (int m = 0; m < 9; m++) q[m] = *(const f32x4*)&xs0[ea][m*52 + u4];
                #pragma unroll
                for (int m = 0; m < 9; m++) {
                    const int l = (m == 0) ? 0 : ((m < 4) ? 1 : 2);
                    const f32x4 wl = (l==0) ? wl0 : ((l==1) ? wl1 : wl2);
                    const f32x4 wv = (l==0) ? ws0 : ((l==1) ? ws1 : ws2);
                    hsc2[m] = PKFMA(LO2(q[m]), LO2(wl), hsc2[m]);
                    hsc2[m] = PKFMA(HI2(q[m]), HI2(wl), hsc2[m]);
                    n0r2[m] = PKFMA(LO2(q[m]), LO2(wv), n0r2[m]);
                    n0r2[m] = PKFMA(HI2(q[m]), HI2(wv), n0r2[m]);
                }
                #pragma unroll
                for (int m = 0; m < 9; m++) q[m] = *(const f32x4*)&xs1[ea][m*52 + u4];
                #pragma unroll
                for (int m = 0; m < 9; m++) {
                    const int l = (m == 0) ? 0 : ((m < 4) ? 1 : 2);
                    const f32x4 wv = (l==0) ? ws0 : ((l==1) ? ws1 : ws2);
                    n1r2[m] = PKFMA(LO2(q[m]), LO2(wv), n1r2[m]);
                    n1r2[m] = PKFMA(HI2(q[m]), HI2(wv), n1r2[m]);
                }
            }
        }
        float hsc[9];
        #pragma unroll
        for (int m = 0; m < 9; m++) hsc[m] = (hsc2[m].x + hsc2[m].y) * S_H;
        __syncthreads();   // A: xs reads done; wls_h copy settled

        if (act) {
            #pragma unroll
            for (int m = 0; m < 9; m++) {
                xs0[ea][m*52 + v] = (n0r2[m].x + n0r2[m].y) * S_CS;
                xs1[ea][m*52 + v] = (n1r2[m].x + n1r2[m].y) * S_CS;
            }
        }
        __syncthreads();   // B

        // ---- P5: tensor-product messages ----
        if (act) {
            const __half* whp = &wls_h[ea][v*15];
            float w[15];
            #pragma unroll
            for (int p = 0; p < 15; p++) w[p] = __half2float(whp[p]);
            float mg[9];
            #pragma unroll
            for (int k = 0; k < 9; ++k) {
                const int l3 = (k == 0) ? 0 : ((k < 4) ? 1 : 2);
                const int kl = k - cSLO[l3];
                float a = 0.f;
                #pragma unroll
                for (int pi = cPL3S[l3]; pi < cPL3S[l3+1]; ++pi) {
                    const int p = cPBYL3[pi];
                    const int l1 = cL1[p];
                    const int D1 = 2*l1 + 1, D3 = 2*l3 + 1;
                    float mm = 0.f;
                    #pragma unroll
                    for (int i = 0; i < D1; ++i)
                        mm += ck[ea][cCKOFF[p] + i*D3 + kl] * hsc[cSLO[l1] + i];
                    a += w[p] * mm;
                }
                mg[k] = a * cINVNP[l3];
            }
            #pragma unroll
            for (int k = 0; k < 9; ++k) msg[ea][k*52 + v] = mg[k];
        }
        __syncthreads();   // C

        // ---- P6: xs1 += lmix(msg, Wlin2) * S_L2; packed-FP32 ----
        if (act) {
            const float* w6 = W6P + (size_t)(L*50 + v) * 156;   // [c3][u52]
            f32x2 am2[9];
            #pragma unroll
            for (int m = 0; m < 9; m++) am2[m] = (f32x2){0.f, 0.f};
            for (int u4 = 0; u4 < 52; u4 += 4) {
                f32x4 w60 = *(const f32x4*)(w6 +   0 + u4);
                f32x4 w61 = *(const f32x4*)(w6 +  52 + u4);
                f32x4 w62 = *(const f32x4*)(w6 + 104 + u4);
                f32x4 q[9];
                #pragma unroll
                for (int m = 0; m < 9; m++) q[m] = *(const f32x4*)&msg[ea][m*52 + u4];
                #pragma unroll
                for (int m = 0; m < 9; m++) {
                    const int l = (m == 0) ? 0 : ((m < 4) ? 1 : 2);
                    const f32x4 wv = (l==0) ? w60 : ((l==1) ? w61 : w62);
                    am2[m] = PKFMA(LO2(q[m]), LO2(wv), am2[m]);
                    am2[m] = PKFMA(HI2(q[m]), HI2(wv), am2[m]);
                }
            }
            #pragma unroll
            for (int m = 0; m < 9; m++)
                xs1[ea][m*52 + v] += (am2[m].x + am2[m].y) * S_L2;
        }
        __syncthreads();   // D

        // ---- P7: gate matmuls -> REGISTERS; packed-FP32 ----
        float g0 = 0.f, g1 = 0.f;
        if (act) {
            const float* wg = WGT + (L*50 + v) * 52;
            f32x2 a02 = (f32x2){0.f, 0.f}, a12 = (f32x2){0.f, 0.f};
            #pragma unroll
            for (int u4 = 0; u4 < 52; u4 += 4) {
                f32x4 wv = *(const f32x4*)(wg + u4);
                f32x4 x0 = *(const f32x4*)&xs0[ea][u4];   // m=0 row
                f32x4 x1 = *(const f32x4*)&xs1[ea][u4];
                a02 = PKFMA(LO2(x0), LO2(wv), a02);
                a02 = PKFMA(HI2(x0), HI2(wv), a02);
                a12 = PKFMA(LO2(x1), LO2(wv), a12);
                a12 = PKFMA(HI2(x1), HI2(wv), a12);
            }
            g0 = sigf((a02.x + a02.y) * S_H);
            g1 = sigf((a12.x + a12.y) * S_H);
        }
        __syncthreads();   // E: all P7 xs reads done before P8 writes

        // ---- P8: gate apply, act-owned ----
        if (act) {
            float* p0 = &xs0[ea][v];
            float* p1 = &xs1[ea][v];
            float s0 = p0[0], s1 = p1[0];
            p0[0] = s0 * sigf(s0);
            p1[0] = s1 * sigf(s1);
            #pragma unroll
            for (int m = 1; m < 9; m++) { p0[m*52] *= g0; p1[m*52] *= g1; }
        }
        __syncthreads();   // F
    }

    // ---- Output projection: rows (1+m) are u-contiguous ----
    if (t < NE5*6) {
        int e = t / 6, r = t % 6, half = r / 3, m = r % 3;
        const float* xp = half ? &xs1[e][(1 + m)*52] : &xs0[e][(1 + m)*52];
        float a = 0;
        #pragma unroll 2
        for (int u = 0; u < 50; ++u) a += xp[u] * Wout[u];
        out[((size_t)(2*(e0 + e) + half))*3 + m] = a * S_H;
    }
}

// ---------------- launch ----------------
extern "C" void kernel_launch(void* const* d_in, const int* in_sizes, int n_in,
                              void* d_out, int out_size, void* d_ws, size_t ws_size,
                              hipStream_t stream) {
    const float* node_pos = (const float*)d_in[0];
    const float* bar      = (const float*)d_in[1];
    const float* Wemb     = (const float*)d_in[2];
    const float* Wsc      = (const float*)d_in[3];
    const float* Wlin1    = (const float*)d_in[4];
    const float* W1       = (const float*)d_in[5];
    const float* b1       = (const float*)d_in[6];
    const float* W2       = (const float*)d_in[7];
    const float* Wlin2    = (const float*)d_in[8];
    const float* Wgate    = (const float*)d_in[9];
    const float* Wout     = (const float*)d_in[10];
    float* out = (float*)d_out;
    float* ws  = (float*)d_ws;

    W3J w3j;
    build_w3j(w3j);

    k_pack<<<1024, 256, 0, stream>>>(Wsc, Wlin1, Wlin2, Wgate, W1, W2, ws);
    k_wls<<<1875, 256, 0, stream>>>(node_pos, b1, ws);
    k_fused_pre<<<E_EDGES/NE5, 256, 0, stream>>>(node_pos, bar, Wemb, Wout, ws, out, w3j);
}

// Round 18
// 584.698 us; speedup vs baseline: 1.9954x; 1.3740x over previous
//
#include <hip/hip_runtime.h>
#include <hip/hip_fp16.h>
#include <math.h>
#include <string.h>

// ---------------- problem constants ----------------
#define E_EDGES 40000
#define N_NODES 80000
#define NE5 5         // edges per block

// ---- sign knobs (verified correct in round 1) ----
#define S111 1.0
#define S122 1.0
#define S212 1.0
#define S221 1.0
#define S222 1.0

struct W3J { float v[615]; };

typedef __attribute__((ext_vector_type(8))) short bf16x8;
typedef __attribute__((ext_vector_type(4))) float f32x4;
typedef _Float16 h16x2 __attribute__((ext_vector_type(2)));
typedef _Float16 h16x8 __attribute__((ext_vector_type(8)));

// ---------------- host: build W3J tensors (verified round 1) ----------------
static void build_w3j(W3J& w) {
    const double s3 = sqrt(3.0), s5 = sqrt(5.0), s15 = sqrt(15.0);
    struct Mono { int a, b, c; double co; };
    Mono Y[3][5][3]; int nm[3][5];
    for (int l = 0; l < 3; l++) for (int c = 0; c < 5; c++) nm[l][c] = 0;
    nm[0][0] = 1; Y[0][0][0] = Mono{0,0,0,1.0};
    nm[1][0] = 1; Y[1][0][0] = Mono{1,0,0,s3};
    nm[1][1] = 1; Y[1][1][0] = Mono{0,1,0,s3};
    nm[1][2] = 1; Y[1][2][0] = Mono{0,0,1,s3};
    nm[2][0] = 1; Y[2][0][0] = Mono{1,0,1,s15};
    nm[2][1] = 1; Y[2][1][0] = Mono{1,1,0,s15};
    nm[2][2] = 3; Y[2][2][0] = Mono{0,2,0,s5};  Y[2][2][1] = Mono{2,0,0,-0.5*s5}; Y[2][2][2] = Mono{0,0,2,-0.5*s5};
    nm[2][3] = 1; Y[2][3][0] = Mono{0,1,1,s15};
    nm[2][4] = 2; Y[2][4][0] = Mono{0,0,2,0.5*s15}; Y[2][4][1] = Mono{2,0,0,-0.5*s15};

    static const int PL[15][3] = {{0,0,0},{0,1,1},{0,2,2},{1,0,1},{1,1,0},{1,1,1},{1,1,2},{1,2,1},
                                  {1,2,2},{2,0,2},{2,1,1},{2,1,2},{2,2,0},{2,2,1},{2,2,2}};
    static const int OFF[15]  = {0,1,10,35,44,53,80,125,170,245,270,315,390,415,490};
    static const int ANCH[15] = {0,0,0,0,0,5,22,22,29,0,22,9,0,13,2};
    const double ASGN[15] = {1,1,1,1,1, S111, 1,1, S122, 1,1, S212, 1, S221, S222};

    auto dfact = [](int n) { double r = 1.0; for (int k = n; k > 1; k -= 2) r *= k; return r; };

    double Mm[5][3][3]; memset(Mm, 0, sizeof(Mm));
    const double mh = s15 * 0.5;
    Mm[0][0][2] = Mm[0][2][0] = mh;
    Mm[1][0][1] = Mm[1][1][0] = mh;
    Mm[2][0][0] = -0.5*s5; Mm[2][1][1] = s5; Mm[2][2][2] = -0.5*s5;
    Mm[3][1][2] = Mm[3][2][1] = mh;
    Mm[4][0][0] = -mh; Mm[4][2][2] = mh;
    double T[3][5][5];
    for (int a = 0; a < 5; a++) for (int b = 0; b < 5; b++) {
        double K[3][3];
        for (int i = 0; i < 3; i++) for (int j = 0; j < 3; j++) {
            double ab = 0, ba = 0;
            for (int r = 0; r < 3; r++) { ab += Mm[a][i][r]*Mm[b][r][j]; ba += Mm[b][i][r]*Mm[a][r][j]; }
            K[i][j] = ab - ba;
        }
        T[0][a][b] = K[1][2]; T[1][a][b] = K[2][0]; T[2][a][b] = K[0][1];
    }

    for (int p = 0; p < 15; p++) {
        int l1 = PL[p][0], l2 = PL[p][1], l3 = PL[p][2];
        int d1 = 2*l1+1, d2 = 2*l2+1, d3 = 2*l3+1, d = d1*d2*d3;
        double tt[125];
        if (((l1 + l2 + l3) & 1) == 0) {
            for (int i = 0; i < d1; i++) for (int j = 0; j < d2; j++) for (int k = 0; k < d3; k++) {
                double a = 0;
                for (int q1 = 0; q1 < nm[l1][i]; q1++)
                for (int q2 = 0; q2 < nm[l2][j]; q2++)
                for (int q3 = 0; q3 < nm[l3][k]; q3++) {
                    const Mono& A = Y[l1][i][q1]; const Mono& B = Y[l2][j][q2]; const Mono& C = Y[l3][k][q3];
                    int xa = A.a+B.a+C.a, yb = A.b+B.b+C.b, zc = A.c+B.c+C.c;
                    if ((xa & 1) || (yb & 1) || (zc & 1)) continue;
                    a += A.co*B.co*C.co * dfact(xa-1)*dfact(yb-1)*dfact(zc-1) / dfact(xa+yb+zc+1);
                }
                tt[(i*d2 + j)*d3 + k] = a;
            }
        } else if (p == 5) {
            for (int q = 0; q < 27; q++) tt[q] = 0;
            tt[0*9+1*3+2] = 1; tt[1*9+2*3+0] = 1; tt[2*9+0*3+1] = 1;
            tt[0*9+2*3+1] = -1; tt[1*9+0*3+2] = -1; tt[2*9+1*3+0] = -1;
        } else {
            for (int q = 0; q < d; q++) tt[q] = 0;
            if (p == 8)  for (int i=0;i<3;i++) for(int a=0;a<5;a++) for(int b=0;b<5;b++) tt[(i*5+a)*5+b] = T[i][a][b];
            if (p == 11) for (int a=0;a<5;a++) for(int i=0;i<3;i++) for(int b=0;b<5;b++) tt[(a*3+i)*5+b] = T[i][a][b];
            if (p == 13) for (int a=0;a<5;a++) for(int b=0;b<5;b++) for(int i=0;i<3;i++) tt[(a*5+b)*3+i] = T[i][a][b];
        }
        double nrm = 0; for (int q = 0; q < d; q++) nrm += tt[q]*tt[q];
        nrm = sqrt(nrm);
        double sg = ((tt[ANCH[p]] >= 0) ? 1.0 : -1.0) * ASGN[p] / nrm;
        for (int q = 0; q < d; q++) w.v[OFF[p] + q] = (float)(tt[q] * sg);
    }
}

// ---------------- device tables (runtime-indexed, ck phase only) ----------------
__device__ const int d_L2r[15]    = {0,1,2,0,1,1,1,2,2,0,1,1,2,2,2};
__device__ const int d_L3r[15]    = {0,1,2,1,0,1,2,1,2,2,1,2,0,1,2};
__device__ const int d_OFFr[15]   = {0,1,10,35,44,53,80,125,170,245,270,315,390,415,490};
__device__ const int d_CKOFFr[15] = {0,1,4,9,18,21,30,45,54,69,94,109,134,139,154};
__device__ const int d_SLOr[3]    = {0,1,4};

#define S_H  0.1414213562373095f    // 1/sqrt(50)
#define S_CS 0.13065629648763766f   // cos(pi/8)/sqrt(50)
#define S_L2 0.03826834323650898f   // sin(pi/8)/10

// ---- d_ws layout ----
// floats:  [0,3600)           W1T [3][100][12]
// ushorts: float off 3600     W2F 2 planes x 288768 ushorts
// halves (byte offsets):
#define WS_W1T 0
#define WS_W2F 3600
#define W2F_PLANE 288768
#define HB_WP3 1169472   // (3600+288768)*4 ; WP3H [3][50][6][56] halves
#define HB_W6P 1270272   // +50400*2       ; W6PH [3][50][3][56]
#define HB_WGT 1320672   // +25200*2       ; WGTH [3][50][56]
#define WLS_BYTE_OFF 1337472  // +8400*2 ; wls fp16 [3][40000][752]

__device__ __forceinline__ float sigf(float a) { return 1.0f / (1.0f + expf(-a)); }

__device__ __forceinline__ unsigned bf16_rne(float v) {
    unsigned x = __float_as_uint(v);
    return (x + 0x7FFFu + ((x >> 16) & 1u)) >> 16;
}

#define BUILD_B(KS, BH, BL, TP) { \
    _Pragma("unroll") \
    for (int i_ = 0; i_ < 8; i_++) { \
        float v_ = (TP)[(KS)*32 + (lane >> 4)*8 + i_]; \
        unsigned h_ = bf16_rne(v_); \
        (BH)[i_] = (short)h_; \
        (BL)[i_] = (short)bf16_rne(v_ - __uint_as_float(h_ << 16)); \
    } }

#define TILE_MFMA(KS, BH, BL) { \
    const ushort* ap_ = baseA + (((size_t)tile*4 + (KS))*64 + lane)*8; \
    bf16x8 Ah_ = *(const bf16x8*)ap_; \
    bf16x8 Al_ = *(const bf16x8*)(ap_ + W2F_PLANE); \
    acc = __builtin_amdgcn_mfma_f32_16x16x32_bf16(Ah_, (BH), acc, 0, 0, 0); \
    acc = __builtin_amdgcn_mfma_f32_16x16x32_bf16(Ah_, (BL), acc, 0, 0, 0); \
    acc = __builtin_amdgcn_mfma_f32_16x16x32_bf16(Al_, (BH), acc, 0, 0, 0); }

// 8-wide fp16 dot accumulate via v_dot2_f32_f16 (shuffles are register aliases)
#define DOT8(ACC, A, B) { \
    ACC = __builtin_amdgcn_fdot2(__builtin_shufflevector((A),(A),0,1), __builtin_shufflevector((B),(B),0,1), ACC, false); \
    ACC = __builtin_amdgcn_fdot2(__builtin_shufflevector((A),(A),2,3), __builtin_shufflevector((B),(B),2,3), ACC, false); \
    ACC = __builtin_amdgcn_fdot2(__builtin_shufflevector((A),(A),4,5), __builtin_shufflevector((B),(B),4,5), ACC, false); \
    ACC = __builtin_amdgcn_fdot2(__builtin_shufflevector((A),(A),6,7), __builtin_shufflevector((B),(B),6,7), ACC, false); }

// ---------------- one-time weight repack ----------------
__global__ void k_pack(const float* __restrict__ Wsc, const float* __restrict__ Wlin1,
                       const float* __restrict__ Wlin2, const float* __restrict__ Wgate,
                       const float* __restrict__ W1, const float* __restrict__ W2,
                       float* __restrict__ ws) {
    // fp32: W1T
    for (int i = blockIdx.x*blockDim.x + threadIdx.x; i < 3600; i += gridDim.x*blockDim.x) {
        int b = i % 12, j = (i/12) % 100, L = i / 1200;
        ws[WS_W1T + i] = (b < 10) ? W1[L*1000 + b*100 + j] : 0.0f;
    }
    // fp16 lmix/gate weights
    _Float16* hw = (_Float16*)((char*)ws + HB_WP3);
    for (int h = blockIdx.x*blockDim.x + threadIdx.x; h < 84000; h += gridDim.x*blockDim.x) {
        float val = 0.0f;
        if (h < 50400) {                        // WP3H [L][v][c6][u56]
            int u = h % 56, r = h / 56;
            int c = r % 6, v = (r/6) % 50, L = r / 300;
            if (u < 50) {
                if (c < 3) val = Wlin1[L*7500 + c*2500 + u*50 + v];
                else       val = Wsc  [L*7500 + (c-3)*2500 + u*50 + v];
            }
        } else if (h < 75600) {                 // W6PH [L][v][c3][u56]
            int q = h - 50400;
            int u = q % 56, r = q / 56;
            int c = r % 3, v = (r/3) % 50, L = r / 150;
            if (u < 50) val = Wlin2[L*7500 + c*2500 + u*50 + v];
        } else {                                // WGTH [L][v][u56]
            int q = h - 75600;
            int u = q % 56, r = q / 56;
            int v = r % 50, L = r / 50;
            if (u < 50) val = Wgate[L*2500 + u*50 + v];
        }
        hw[h] = (_Float16)val;
    }
    // W2 bf16 hi/lo fragment planes (for k_wls MFMA)
    ushort* w2f = (ushort*)(ws + WS_W2F);
    for (int q = blockIdx.x*blockDim.x + threadIdx.x; q < 2*W2F_PLANE; q += gridDim.x*blockDim.x) {
        int plane = q / W2F_PLANE, r = q % W2F_PLANE;
        int i = r & 7, lane = (r >> 3) & 63, ks = (r >> 9) & 3, tl = r >> 11;
        int tile = tl % 47, L = tl / 47;
        int o = tile*16 + (lane & 15);
        int k = ks*32 + (lane >> 4)*8 + i;
        float w = (k < 100 && o < 750) ? W2[L*75000 + k*750 + o] : 0.0f;
        unsigned h = bf16_rne(w);
        unsigned val;
        if (plane == 0) val = h;
        else {
            float fh = __uint_as_float(h << 16);
            val = bf16_rne(w - fh);
        }
        w2f[q] = (ushort)val;
    }
}

// ---------------- wls precompute (verified rounds 7-17; pointer offsets only) ----------------
__global__ __launch_bounds__(256, 3) void k_wls(
    const float* __restrict__ node_pos, const float* __restrict__ b1,
    float* __restrict__ ws)
{
    __shared__ __align__(16) float embw[64][12];
    __shared__ __align__(16) float t100s[64][132];
    __shared__ __align__(16) float stage[4][16][20];
    const int t = threadIdx.x;
    const int bid = blockIdx.x;
    const int Lidx = bid / 625;
    const int e0 = (bid % 625) * 64;
    const float* W1T = ws + WS_W1T;
    const ushort* W2F = (const ushort*)(ws + WS_W2F);
    __half* wls_g = (__half*)((char*)ws + WLS_BYTE_OFF);

    if (t < 64) {
        const float* np = node_pos + (size_t)(e0 + t) * 6;
        float vx = np[1] - np[0], vy = np[3] - np[2], vz = np[5] - np[4];
        float r = sqrtf(vx*vx + vy*vy + vz*vz);
        const float step = 4.0f / 11.0f;
        const float RC = (float)(1.14136 * 7.3890560989306495 * 3.1622776601683795);
        #pragma unroll
        for (int b = 0; b < 10; b++) {
            float center = step * (b + 1);
            float diff = (r - center) / step;
            float x1 = diff + 1.0f, x2 = 1.0f - diff;
            float u1 = (x1 > 0.0f) ? expf(-1.0f/x1) : 0.0f;
            float u2 = (x2 > 0.0f) ? expf(-1.0f/x2) : 0.0f;
            embw[t][b] = RC * u1 * u2;
        }
        embw[t][10] = 0.0f; embw[t][11] = 0.0f;
    }
    __syncthreads();

    for (int idx = t; idx < 64*132; idx += 256) {
        int e = idx / 132, j = idx % 132;
        float g = 0.0f;
        if (j < 100) {
            const float* wj = W1T + (Lidx*100 + j)*12;
            float4 wa = *(const float4*)wj;
            float4 wb = *(const float4*)(wj + 4);
            float2 wc = *(const float2*)(wj + 8);
            float4 e0v = *(const float4*)&embw[e][0];
            float4 e1v = *(const float4*)&embw[e][4];
            float2 e2v = *(const float2*)&embw[e][8];
            float a = wa.x*e0v.x + wa.y*e0v.y + wa.z*e0v.z + wa.w*e0v.w
                    + wb.x*e1v.x + wb.y*e1v.y + wb.z*e1v.z + wb.w*e1v.w
                    + wc.x*e2v.x + wc.y*e2v.y;
            a = a * 0.31622776601683794f + b1[Lidx*100 + j];
            float th = tanhf(0.7978845608028654f * (a + 0.044715f * a*a*a));
            g = 0.5f * a * (1.0f + th);
        }
        t100s[e][j] = g;
    }
    __syncthreads();

    const int lane = t & 63, wave = t >> 6;
    const int bcol = lane & 15, bg = lane >> 4;
    const ushort* baseA = W2F + (size_t)Lidx * (47*4*64*8);
    __half* wout = wls_g + (size_t)(Lidx*40000 + e0) * 752;

    for (int eg = 0; eg < 4; eg++) {
        const float* tp = &t100s[eg*16 + bcol][0];
        bf16x8 Bh0, Bh1, Bh2, Bh3, Bl0, Bl1, Bl2, Bl3;
        BUILD_B(0, Bh0, Bl0, tp) BUILD_B(1, Bh1, Bl1, tp)
        BUILD_B(2, Bh2, Bl2, tp) BUILD_B(3, Bh3, Bl3, tp)
        for (int tile = wave; tile < 47; tile += 4) {
            f32x4 acc = {0.f, 0.f, 0.f, 0.f};
            TILE_MFMA(0, Bh0, Bl0) TILE_MFMA(1, Bh1, Bl1)
            TILE_MFMA(2, Bh2, Bl2) TILE_MFMA(3, Bh3, Bl3)
            *(float4*)&stage[wave][bcol][bg*4] = make_float4(acc[0], acc[1], acc[2], acc[3]);
            int er = lane >> 2, o4 = (lane & 3) * 4;
            float4 vv = *(const float4*)&stage[wave][er][o4];
            __half2 p0 = __floats2half2_rn(vv.x * 0.1f, vv.y * 0.1f);
            __half2 p1 = __floats2half2_rn(vv.z * 0.1f, vv.w * 0.1f);
            union { __half2 h2[2]; uint2 u2; } pk;
            pk.h2[0] = p0; pk.h2[1] = p1;
            *(uint2*)(wout + (size_t)(eg*16 + er)*752 + tile*16 + o4) = pk.u2;
        }
    }
}

// ---------------- fused 3-layer kernel: fp16 state + fdot2 (round-11 structure) ----------------
// [m][u56] fp16 state: each b128 covers 8 u -> LDS-read instrs ~halved vs round 17.
// LDS 26.5 KB -> 6 blocks/CU (24 waves). fdot2 keeps VALU instr count unchanged.
__global__ __launch_bounds__(256, 4) void k_fused_pre(
    const float* __restrict__ node_pos, const float* __restrict__ bar,
    const float* __restrict__ Wemb, const float* __restrict__ Wout,
    const float* __restrict__ ws, float* __restrict__ out, W3J w3j)
{
    __shared__ __align__(16) _Float16 xs0[NE5][504];   // [m][u56]
    __shared__ __align__(16) _Float16 xs1[NE5][504];
    __shared__ __align__(16) _Float16 msg[NE5][504];
    __shared__ __align__(16) _Float16 wls_h[NE5][752];
    __shared__ __align__(16) float ck[NE5][180];
    __shared__ __align__(16) float shs[NE5][12];       // 0..8 sh, 9..10 bar pair

    const int t = threadIdx.x;
    const int e0 = blockIdx.x * NE5;

    constexpr int cL1[15]    = {0,0,0,1,1,1,1,1,1,2,2,2,2,2,2};
    constexpr int cCKOFF[15] = {0,1,4,9,18,21,30,45,54,69,94,109,134,139,154};
    constexpr int cSLO[3]    = {0,1,4};
    constexpr int cPBYL3[15] = {0,4,12, 1,3,5,7,10,13, 2,6,8,9,11,14};
    constexpr int cPL3S[4]   = {0,3,9,15};
    constexpr float cINVNP[3] = {0.57735026918962584f, 0.40824829046386302f, 0.40824829046386302f};

    const _Float16* WP3H = (const _Float16*)((const char*)ws + HB_WP3);
    const _Float16* W6PH = (const _Float16*)((const char*)ws + HB_W6P);
    const _Float16* WGTH = (const _Float16*)((const char*)ws + HB_WGT);
    const _Float16* wls_g = (const _Float16*)((const char*)ws + WLS_BYTE_OFF);

    // ---- Phase A: per-edge sh + bar ----
    if (t < NE5) {
        const int e = t;
        const float* np = node_pos + (size_t)(e0 + e) * 6;
        float vx = np[1] - np[0], vy = np[3] - np[2], vz = np[5] - np[4];
        float r = sqrtf(vx*vx + vy*vy + vz*vz);
        float inv = 1.0f / fmaxf(r, 1e-12f);
        float x = vx*inv, y = vy*inv, z = vz*inv;
        const float s3 = 1.7320508075688772f, s5 = 2.23606797749979f, s15 = 3.872983346207417f;
        shs[e][0] = 1.0f;
        shs[e][1] = s3*x; shs[e][2] = s3*y; shs[e][3] = s3*z;
        shs[e][4] = s15*x*z; shs[e][5] = s15*x*y;
        shs[e][6] = s5*(y*y - 0.5f*(x*x + z*z));
        shs[e][7] = s15*y*z;
        shs[e][8] = 0.5f*s15*(z*z - x*x);
    }
    if (t >= 64 && t < 64 + 2*NE5) {
        int q = t - 64;
        shs[q >> 1][9 + (q & 1)] = bar[2*e0 + q];
    }
    __syncthreads();

    // ---- Phase B: ck build + x init (fp16, pads zeroed) + msg pads ----
    for (int idx = t; idx < NE5*179; idx += 256) {
        int e = idx / 179, q = idx % 179;
        int p = 0; while (p < 14 && q >= d_CKOFFr[p+1]) p++;
        int rem = q - d_CKOFFr[p];
        int D2 = 2*d_L2r[p] + 1, D3 = 2*d_L3r[p] + 1;
        int i = rem / D3, k = rem % D3;
        const float* C = w3j.v + d_OFFr[p];
        const float* s = &shs[e][d_SLOr[d_L2r[p]]];
        float a = 0;
        for (int j = 0; j < D2; j++) a += C[(i*D2 + j)*D3 + k] * s[j];
        ck[e][q] = a;
    }
    for (int idx = t; idx < 2*NE5*504; idx += 256) {
        int n = idx / 504, i = idx % 504;
        int e = n >> 1, half = n & 1;
        int m = i / 56, u = i % 56;
        float val = (m == 0 && u < 50) ? shs[e][9 + half] * Wemb[u] : 0.0f;
        if (half) xs1[e][i] = (_Float16)val; else xs0[e][i] = (_Float16)val;
    }
    for (int idx = t; idx < NE5*54; idx += 256) {   // msg pads u=50..55
        int e = idx / 54, r = idx % 54;
        int m = r / 6, p = r % 6;
        msg[e][m*56 + 50 + p] = (_Float16)0.0f;
    }
    __syncthreads();

    const bool act = (t < 50*NE5);
    const int v = t / NE5, ea = t % NE5;

    // ================== 3 layers, all in LDS ==================
    for (int L = 0; L < 3; L++) {
        // ---- wls global->LDS raw fp16 copy; hides under P3 ----
        {
            const _Float16* wsrc = wls_g + (size_t)(L*40000 + e0) * 752;
            for (int idx = t; idx < NE5*94; idx += 256) {
                int e = idx / 94, c = idx % 94;
                *(uint4*)&wls_h[e][c*8] = *(const uint4*)(wsrc + (size_t)e*752 + c*8);
            }
        }

        // ---- P3: three lmixes; fp16 state/weights, fdot2 ----
        float hsc[9], n0r[9], n1r[9];
        #pragma unroll
        for (int m = 0; m < 9; m++) { hsc[m] = 0.f; n0r[m] = 0.f; n1r[m] = 0.f; }
        if (act) {
            const _Float16* wp = WP3H + (size_t)(L*50 + v) * 336;   // [c6][u56]
            for (int u8 = 0; u8 < 56; u8 += 8) {
                h16x8 wl0 = *(const h16x8*)(wp +   0 + u8);
                h16x8 wl1 = *(const h16x8*)(wp +  56 + u8);
                h16x8 wl2 = *(const h16x8*)(wp + 112 + u8);
                h16x8 ws0 = *(const h16x8*)(wp + 168 + u8);
                h16x8 ws1 = *(const h16x8*)(wp + 224 + u8);
                h16x8 ws2 = *(const h16x8*)(wp + 280 + u8);
                h16x8 q[9];
                #pragma unroll
                for (int m = 0; m < 9; m++) q[m] = *(const h16x8*)&xs0[ea][m*56 + u8];
                #pragma unroll
                for (int m = 0; m < 9; m++) {
                    const int l = (m == 0) ? 0 : ((m < 4) ? 1 : 2);
                    const h16x8 wl = (l==0) ? wl0 : ((l==1) ? wl1 : wl2);
                    const h16x8 wv = (l==0) ? ws0 : ((l==1) ? ws1 : ws2);
                    DOT8(hsc[m], q[m], wl)
                    DOT8(n0r[m], q[m], wv)
                }
                #pragma unroll
                for (int m = 0; m < 9; m++) q[m] = *(const h16x8*)&xs1[ea][m*56 + u8];
                #pragma unroll
                for (int m = 0; m < 9; m++) {
                    const int l = (m == 0) ? 0 : ((m < 4) ? 1 : 2);
                    const h16x8 wv = (l==0) ? ws0 : ((l==1) ? ws1 : ws2);
                    DOT8(n1r[m], q[m], wv)
                }
            }
            #pragma unroll
            for (int m = 0; m < 9; m++) hsc[m] *= S_H;
        }
        __syncthreads();   // A: xs reads done; wls_h copy settled

        if (act) {
            #pragma unroll
            for (int m = 0; m < 9; m++) {
                xs0[ea][m*56 + v] = (_Float16)(n0r[m] * S_CS);
                xs1[ea][m*56 + v] = (_Float16)(n1r[m] * S_CS);
            }
        }
        __syncthreads();   // B

        // ---- P5: tensor-product messages ----
        if (act) {
            const _Float16* whp = &wls_h[ea][v*15];
            float w[15];
            #pragma unroll
            for (int p = 0; p < 15; p++) w[p] = (float)whp[p];
            float mg[9];
            #pragma unroll
            for (int k = 0; k < 9; ++k) {
                const int l3 = (k == 0) ? 0 : ((k < 4) ? 1 : 2);
                const int kl = k - cSLO[l3];
                float a = 0.f;
                #pragma unroll
                for (int pi = cPL3S[l3]; pi < cPL3S[l3+1]; ++pi) {
                    const int p = cPBYL3[pi];
                    const int l1 = cL1[p];
                    const int D1 = 2*l1 + 1, D3 = 2*l3 + 1;
                    float mm = 0.f;
                    #pragma unroll
                    for (int i = 0; i < D1; ++i)
                        mm += ck[ea][cCKOFF[p] + i*D3 + kl] * hsc[cSLO[l1] + i];
                    a += w[p] * mm;
                }
                mg[k] = a * cINVNP[l3];
            }
            #pragma unroll
            for (int k = 0; k < 9; ++k) msg[ea][k*56 + v] = (_Float16)mg[k];
        }
        __syncthreads();   // C

        // ---- P6: xs1 += lmix(msg, Wlin2) * S_L2; fdot2 ----
        if (act) {
            const _Float16* w6 = W6PH + (size_t)(L*50 + v) * 168;   // [c3][u56]
            float am[9];
            #pragma unroll
            for (int m = 0; m < 9; m++) am[m] = 0.f;
            for (int u8 = 0; u8 < 56; u8 += 8) {
                h16x8 w60 = *(const h16x8*)(w6 +   0 + u8);
                h16x8 w61 = *(const h16x8*)(w6 +  56 + u8);
                h16x8 w62 = *(const h16x8*)(w6 + 112 + u8);
                h16x8 q[9];
                #pragma unroll
                for (int m = 0; m < 9; m++) q[m] = *(const h16x8*)&msg[ea][m*56 + u8];
                #pragma unroll
                for (int m = 0; m < 9; m++) {
                    const int l = (m == 0) ? 0 : ((m < 4) ? 1 : 2);
                    const h16x8 wv = (l==0) ? w60 : ((l==1) ? w61 : w62);
                    DOT8(am[m], q[m], wv)
                }
            }
            #pragma unroll
            for (int m = 0; m < 9; m++) {
                float old = (float)xs1[ea][m*56 + v];
                xs1[ea][m*56 + v] = (_Float16)(old + am[m] * S_L2);
            }
        }
        __syncthreads();   // D

        // ---- P7: gate matmuls -> REGISTERS; fdot2 ----
        float g0 = 0.f, g1 = 0.f;
        if (act) {
            const _Float16* wg = WGTH + (size_t)(L*50 + v) * 56;
            float a0 = 0.f, a1 = 0.f;
            #pragma unroll
            for (int u8 = 0; u8 < 56; u8 += 8) {
                h16x8 wv = *(const h16x8*)(wg + u8);
                h16x8 x0 = *(const h16x8*)&xs0[ea][u8];   // m=0 row
                h16x8 x1 = *(const h16x8*)&xs1[ea][u8];
                DOT8(a0, x0, wv)
                DOT8(a1, x1, wv)
            }
            g0 = sigf(a0 * S_H);
            g1 = sigf(a1 * S_H);
        }
        __syncthreads();   // E: all P7 xs reads done before P8 writes

        // ---- P8: gate apply, act-owned ----
        if (act) {
            _Float16* p0 = &xs0[ea][v];
            _Float16* p1 = &xs1[ea][v];
            float s0 = (float)p0[0], s1 = (float)p1[0];
            p0[0] = (_Float16)(s0 * sigf(s0));
            p1[0] = (_Float16)(s1 * sigf(s1));
            #pragma unroll
            for (int m = 1; m < 9; m++) {
                p0[m*56] = (_Float16)((float)p0[m*56] * g0);
                p1[m*56] = (_Float16)((float)p1[m*56] * g1);
            }
        }
        __syncthreads();   // F
    }

    // ---- Output projection: rows (1+m) are u-contiguous ----
    if (t < NE5*6) {
        int e = t / 6, r = t % 6, half = r / 3, m = r % 3;
        const _Float16* xp = half ? &xs1[e][(1 + m)*56] : &xs0[e][(1 + m)*56];
        float a = 0;
        #pragma unroll 2
        for (int u = 0; u < 50; ++u) a += (float)xp[u] * Wout[u];
        out[((size_t)(2*(e0 + e) + half))*3 + m] = a * S_H;
    }
}

// ---------------- launch ----------------
extern "C" void kernel_launch(void* const* d_in, const int* in_sizes, int n_in,
                              void* d_out, int out_size, void* d_ws, size_t ws_size,
                              hipStream_t stream) {
    const float* node_pos = (const float*)d_in[0];
    const float* bar      = (const float*)d_in[1];
    const float* Wemb     = (const float*)d_in[2];
    const float* Wsc      = (const float*)d_in[3];
    const float* Wlin1    = (const float*)d_in[4];
    const float* W1       = (const float*)d_in[5];
    const float* b1       = (const float*)d_in[6];
    const float* W2       = (const float*)d_in[7];
    const float* Wlin2    = (const float*)d_in[8];
    const float* Wgate    = (const float*)d_in[9];
    const float* Wout     = (const float*)d_in[10];
    float* out = (float*)d_out;
    float* ws  = (float*)d_ws;

    W3J w3j;
    build_w3j(w3j);

    k_pack<<<1024, 256, 0, stream>>>(Wsc, Wlin1, Wlin2, Wgate, W1, W2, ws);
    k_wls<<<1875, 256, 0, stream>>>(node_pos, b1, ws);
    k_fused_pre<<<E_EDGES/NE5, 256, 0, stream>>>(node_pos, bar, Wemb, Wout, ws, out, w3j);
}